// Round 4
// baseline (149.157 us; speedup 1.0000x reference)
//
#include <hip/hip_runtime.h>
#include <math.h>

// Problem constants (fixed by setup_inputs)
#define BB 32
#define LL 128
#define DD 300
#define PD 50
#define KW 12          // window K
#define NP 3044        // number of (emo,cau) pairs for L=128, K=12
#define FF 650         // 2*D + pos_dim
#define NR 25          // 2K+1 distinct relative positions
#define KP 320         // K padded for MFMA (10 x 32)
#define MM 4096        // B*L
#define LN_EPS 1e-5f

typedef __attribute__((ext_vector_type(8))) short short8;
typedef __attribute__((ext_vector_type(4))) float f32x4;
typedef __attribute__((ext_vector_type(4))) int i32x4;

// v_cvt_pk_bf16_f32: D.lo = bf16(S0), D.hi = bf16(S1), RNE
__device__ __forceinline__ unsigned int cvtpk(float lo, float hi) {
    unsigned int r;
    asm("v_cvt_pk_bf16_f32 %0, %1, %2" : "=v"(r) : "v"(lo), "v"(hi));
    return r;
}

__device__ __forceinline__ short8 as_short8(i32x4 v) {
    union { i32x4 i; short8 s; } u; u.i = v; return u.s;
}

__device__ __forceinline__ int row_start(int i) {
    // pairs before emo-row i (L=128, K=12)
    if (i <= 12) return i * 13 + (i * (i - 1)) / 2;
    if (i <= 116) return 222 + 25 * (i - 12);
    int s = i - 116;
    return 2822 + 24 * s - (s * (s - 1)) / 2;
}

// load 8 f32 from src[kb..kb+7] (guard vs DD), cvt bf16, store 16B to LDS
__device__ __forceinline__ void cvt_store8(unsigned short* dst,
                                           const float* src, int kb) {
    float f[8];
    if (kb + 7 < DD) {
        float2 a0 = *(const float2*)(src + kb);
        float2 a1 = *(const float2*)(src + kb + 2);
        float2 a2 = *(const float2*)(src + kb + 4);
        float2 a3 = *(const float2*)(src + kb + 6);
        f[0]=a0.x; f[1]=a0.y; f[2]=a1.x; f[3]=a1.y;
        f[4]=a2.x; f[5]=a2.y; f[6]=a3.x; f[7]=a3.y;
    } else {
        #pragma unroll
        for (int u = 0; u < 8; u++) { int k = kb + u; f[u] = (k < DD) ? src[k] : 0.f; }
    }
    i32x4 w;
    w[0]=cvtpk(f[0],f[1]); w[1]=cvtpk(f[2],f[3]);
    w[2]=cvtpk(f[4],f[5]); w[3]=cvtpk(f[6],f[7]);
    *(i32x4*)dst = w;
}

struct B8 { float f[8]; };

// ---------------------------------------------------------------------------
// fused kernel:
//   blocks 0..24     -> P[r][dd] + SP[r] (row sum) + SP2[r] (row sumsq)
//   blocks 25..280   -> MFMA GEMM  O[z][m][d] = sum_k bf16(x+share) * bf16(W)
//                       epilogue: per-row sum AND sumsq partials, 8-wide pack:
//                       SEp[(z*MM+row)*8 + part] (sum), +4+part (sumsq)
// ---------------------------------------------------------------------------
__global__ __launch_bounds__(512) void fused_kernel(
    const float* __restrict__ h_e, const float* __restrict__ h_c,
    const float* __restrict__ h_share, const float* __restrict__ pos_emb,
    const float* __restrict__ W_hid, const float* __restrict__ b_hid,
    float* __restrict__ E, float* __restrict__ Cc, float* __restrict__ P,
    float* __restrict__ SEp, float* __restrict__ SP, float* __restrict__ SP2)
{
    const int tid = threadIdx.x;

    __shared__ unsigned short Bs[2][160 * 40];   // 2 x 12.8 KB, stride 40 (bank-safe)

    if (blockIdx.x < NR) {
        // ---------------- P prep (+ SP, SP2) ----------------
        __shared__ float sm[PD];
        __shared__ float wsum[8], wsum2[8];
        const int r = blockIdx.x;
        if (tid < PD) {
            float acc = 0.f;
            #pragma unroll
            for (int d2 = 0; d2 < NR; d2++) {
                int ad = d2 - KW; if (ad < 0) ad = -ad;
                float cnt = (float)(LL - ad);
                float diff = (float)(r - d2);
                acc += cnt * expf(-diff * diff) * pos_emb[d2 * PD + tid];
            }
            sm[tid] = acc;
        }
        __syncthreads();
        float mine = 0.f, mine2 = 0.f;
        if (tid < DD) {
            float a = b_hid[tid];
            const float* w = W_hid + (size_t)tid * FF + 2 * DD;
            #pragma unroll
            for (int k = 0; k < PD; k++) a += sm[k] * w[k];
            P[r * DD + tid] = a;
            mine = a;
            mine2 = a * a;
        }
        #pragma unroll
        for (int m = 1; m < 64; m <<= 1) {
            mine  += __shfl_xor(mine, m, 64);
            mine2 += __shfl_xor(mine2, m, 64);
        }
        if ((tid & 63) == 0) { wsum[tid >> 6] = mine; wsum2[tid >> 6] = mine2; }
        __syncthreads();
        if (tid == 0) {
            float s = 0.f, s2 = 0.f;
            #pragma unroll
            for (int w = 0; w < 8; w++) { s += wsum[w]; s2 += wsum2[w]; }
            SP[r] = s;
            SP2[r] = s2;
        }
        return;
    }

    // ---------------- GEMM ----------------
    const int gb = blockIdx.x - NR;                 // 0..255
    const int sg = (gb & 7) * 32 + (gb >> 3);      // XCD-chunked swizzle (256%8==0)
    const int m0 = (sg & 63) * 64;
    const int y  = (sg >> 6) & 1;
    const int z  = sg >> 7;
    const int n0 = y * 160;

    const int wid  = tid >> 6;
    const int lane = tid & 63;
    const int wm = wid & 3;          // M sub-tile (4 x 16)
    const int wn = wid >> 2;         // N half (2 x 80)
    const int nn = lane & 15;
    const int q  = lane >> 4;

    const int row = m0 + wm * 16 + nn;
    const float* xr = (z ? h_c : h_e) + (size_t)row * DD;
    const float* sr = h_share + (size_t)row * DD;
    const float* Wsrc = W_hid + z * DD;

    // staging geometry: 640 items (n=0..159, c=0..3); item a = tid, item b = tid+512
    const int n_a = tid >> 2,        c_a = tid & 3;
    const int d_a = n0 + n_a;                      // always < 300 (max 287)
    const int n_b = (tid + 512) >> 2;
    const int d_b = n0 + n_b;                      // needs <300 guard when n0=160
    const bool has_b = (tid < 128);

    B8 ra, rb;
    float4 ax0, ax1, as0, as1;

    auto loadB = [&](int k0) {
        const float* pa = Wsrc + (size_t)d_a * FF + k0 + c_a * 8;  // 8B aligned
        float2 u0 = *(const float2*)(pa);
        float2 u1 = *(const float2*)(pa + 2);
        float2 u2 = *(const float2*)(pa + 4);
        float2 u3 = *(const float2*)(pa + 6);
        ra.f[0] = u0.x; ra.f[1] = u0.y; ra.f[2] = u1.x; ra.f[3] = u1.y;
        ra.f[4] = u2.x; ra.f[5] = u2.y; ra.f[6] = u3.x; ra.f[7] = u3.y;
        if (has_b) {
            if (d_b < DD) {
                const float* pb = Wsrc + (size_t)d_b * FF + k0 + c_a * 8;
                float2 v0 = *(const float2*)(pb);
                float2 v1 = *(const float2*)(pb + 2);
                float2 v2 = *(const float2*)(pb + 4);
                float2 v3 = *(const float2*)(pb + 6);
                rb.f[0] = v0.x; rb.f[1] = v0.y; rb.f[2] = v1.x; rb.f[3] = v1.y;
                rb.f[4] = v2.x; rb.f[5] = v2.y; rb.f[6] = v3.x; rb.f[7] = v3.y;
            } else {
                #pragma unroll
                for (int u = 0; u < 8; u++) rb.f[u] = 0.f;
            }
        }
    };

    auto writeB = [&](int buf) {
        i32x4 w;
        w[0] = cvtpk(ra.f[0], ra.f[1]); w[1] = cvtpk(ra.f[2], ra.f[3]);
        w[2] = cvtpk(ra.f[4], ra.f[5]); w[3] = cvtpk(ra.f[6], ra.f[7]);
        *(i32x4*)&Bs[buf][n_a * 40 + c_a * 8] = w;
        if (has_b) {
            i32x4 v;
            v[0] = cvtpk(rb.f[0], rb.f[1]); v[1] = cvtpk(rb.f[2], rb.f[3]);
            v[2] = cvtpk(rb.f[4], rb.f[5]); v[3] = cvtpk(rb.f[6], rb.f[7]);
            *(i32x4*)&Bs[buf][n_b * 40 + c_a * 8] = v;
        }
    };

    auto loadA = [&](int k0) {
        const int kb = k0 + q * 8;
        if (kb + 7 < DD) {
            ax0 = *(const float4*)&xr[kb];
            ax1 = *(const float4*)&xr[kb + 4];
            as0 = *(const float4*)&sr[kb];
            as1 = *(const float4*)&sr[kb + 4];
        } else {
            float t[8], u[8];
            #pragma unroll
            for (int uu = 0; uu < 8; uu++) {
                int k = kb + uu;
                t[uu] = (k < DD) ? xr[k] : 0.f;
                u[uu] = (k < DD) ? sr[k] : 0.f;
            }
            ax0 = make_float4(t[0], t[1], t[2], t[3]);
            ax1 = make_float4(t[4], t[5], t[6], t[7]);
            as0 = make_float4(u[0], u[1], u[2], u[3]);
            as1 = make_float4(u[4], u[5], u[6], u[7]);
        }
    };

    f32x4 acc[5];
    #pragma unroll
    for (int f = 0; f < 5; f++) acc[f] = (f32x4){0.f, 0.f, 0.f, 0.f};

    // prologue: stage chunk 0
    loadB(0);
    loadA(0);
    writeB(0);
    __syncthreads();

    #pragma unroll
    for (int k0i = 0; k0i < 10; k0i++) {
        const int cb = k0i & 1;
        const bool more = (k0i < 9);
        const int kn = (k0i + 1) * 32;

        if (more) loadB(kn);                 // next B chunk -> regs (in flight)

        i32x4 af;                            // A frag from prefetched regs
        af[0] = cvtpk(ax0.x + as0.x, ax0.y + as0.y);
        af[1] = cvtpk(ax0.z + as0.z, ax0.w + as0.w);
        af[2] = cvtpk(ax1.x + as1.x, ax1.y + as1.y);
        af[3] = cvtpk(ax1.z + as1.z, ax1.w + as1.w);
        short8 a = as_short8(af);

        if (more) loadA(kn);                 // next A chunk -> regs (in flight)

        #pragma unroll
        for (int f = 0; f < 5; f++) {
            short8 b = *(const short8*)&Bs[cb][(wn * 80 + f * 16 + nn) * 40 + q * 8];
            acc[f] = __builtin_amdgcn_mfma_f32_16x16x32_bf16(a, b, acc[f], 0, 0, 0);
        }

        if (more) {
            writeB(cb ^ 1);                  // convert + ds_write next buffer
            __syncthreads();                 // one barrier per K-step
        }
    }

    // epilogue 1: per-row sum AND sumsq partials (for LN moment precompute)
    const int orow = m0 + wm * 16 + q * 4;   // C/D: row = (lane>>4)*4 + reg
    float rs[4], rq[4];
    #pragma unroll
    for (int r2 = 0; r2 < 4; r2++) {
        float v = 0.f, w2 = 0.f;
        #pragma unroll
        for (int f = 0; f < 5; f++) { v += acc[f][r2]; w2 += acc[f][r2] * acc[f][r2]; }
        #pragma unroll
        for (int m = 1; m < 16; m <<= 1) {
            v  += __shfl_xor(v, m, 64);
            w2 += __shfl_xor(w2, m, 64);
        }
        rs[r2] = v; rq[r2] = w2;
    }
    if (nn == 0) {
        float* sb = SEp + ((size_t)z * MM + orow) * 8;
        const int part = y * 2 + wn;
        #pragma unroll
        for (int r2 = 0; r2 < 4; r2++) {
            sb[r2 * 8 + part]     = rs[r2];
            sb[r2 * 8 + 4 + part] = rq[r2];
        }
    }

    // epilogue 2: C write
    float* O = z ? Cc : E;
    #pragma unroll
    for (int f = 0; f < 5; f++) {
        int col = n0 + wn * 80 + f * 16 + nn;  // C/D: col = lane&15
        if (col < DD) {
            #pragma unroll
            for (int r2 = 0; r2 < 4; r2++)
                O[(size_t)(orow + r2) * DD + col] = acc[f][r2];
        }
    }
}

// ---------------------------------------------------------------------------
// moments kernel: cross-term GEMMs for the sumsq decomposition (bf16 MFMA).
//   blocks 0..31   -> EC[b] = E_b (128x300) . C_b^T  -> [128][128] f32
//   blocks 32..95  -> EP = E . P^T  (rows mb*64..+63, cols r=0..31)
//   blocks 96..159 -> CP = C . P^T
// ---------------------------------------------------------------------------
__global__ __launch_bounds__(256) void moments_kernel(
    const float* __restrict__ E, const float* __restrict__ Cc,
    const float* __restrict__ P, float* __restrict__ EC,
    float* __restrict__ EP, float* __restrict__ CP)
{
    const int tid = threadIdx.x;
    const int wid = tid >> 6;
    const int lane = tid & 63;
    const int nn = lane & 15;
    const int q  = lane >> 4;

    __shared__ unsigned short sbuf[10240];   // 20.5 KB

    if (blockIdx.x < BB) {
        // ---- EC: one block per batch ----
        const int b = blockIdx.x;
        const float* Eb = E  + (size_t)b * LL * DD;
        const float* Cb = Cc + (size_t)b * LL * DD;
        unsigned short* Es = sbuf;            // [128][40]
        unsigned short* Cs = sbuf + 5120;     // [128][40]

        f32x4 acc[2][8];
        #pragma unroll
        for (int mr = 0; mr < 2; mr++)
            #pragma unroll
            for (int f = 0; f < 8; f++) acc[mr][f] = (f32x4){0.f,0.f,0.f,0.f};

        const int m0 = wid * 32;

        for (int k0 = 0; k0 < KP; k0 += 32) {
            __syncthreads();
            #pragma unroll
            for (int it0 = 0; it0 < 2; it0++) {
                int it = tid + it0 * 256;          // 0..511
                int rrow = it >> 2, c = it & 3;
                cvt_store8(&Es[rrow * 40 + c * 8], Eb + rrow * DD, k0 + c * 8);
                cvt_store8(&Cs[rrow * 40 + c * 8], Cb + rrow * DD, k0 + c * 8);
            }
            __syncthreads();
            #pragma unroll
            for (int mr = 0; mr < 2; mr++) {
                short8 a = *(const short8*)&Es[(m0 + mr * 16 + nn) * 40 + q * 8];
                #pragma unroll
                for (int f = 0; f < 8; f++) {
                    short8 bb = *(const short8*)&Cs[(f * 16 + nn) * 40 + q * 8];
                    acc[mr][f] = __builtin_amdgcn_mfma_f32_16x16x32_bf16(a, bb, acc[mr][f], 0, 0, 0);
                }
            }
        }
        float* ECb = EC + (size_t)b * LL * LL;
        #pragma unroll
        for (int mr = 0; mr < 2; mr++) {
            const int orow = m0 + mr * 16 + q * 4;
            #pragma unroll
            for (int f = 0; f < 8; f++) {
                const int col = f * 16 + nn;
                #pragma unroll
                for (int r2 = 0; r2 < 4; r2++)
                    ECb[(orow + r2) * LL + col] = acc[mr][f][r2];
            }
        }
    } else {
        // ---- EP / CP: X (64 rows) . P^T (32 cols) ----
        const int idx2 = blockIdx.x - BB;
        const int which = idx2 >> 6;             // 0: EP (X=E), 1: CP (X=C)
        const int mb = idx2 & 63;
        const float* X = (which ? Cc : E) + (size_t)mb * 64 * DD;
        float* O = which ? CP : EP;
        unsigned short* Xs = sbuf;               // [64][40]
        unsigned short* Ps = sbuf + 2560;        // [32][40]

        f32x4 acc[2];
        acc[0] = (f32x4){0.f,0.f,0.f,0.f};
        acc[1] = (f32x4){0.f,0.f,0.f,0.f};

        for (int k0 = 0; k0 < KP; k0 += 32) {
            __syncthreads();
            { int rrow = tid >> 2, c = tid & 3;
              cvt_store8(&Xs[rrow * 40 + c * 8], X + rrow * DD, k0 + c * 8); }
            if (tid < 128) {
                int rr = tid >> 2, c = tid & 3;
                if (rr < NR) {
                    cvt_store8(&Ps[rr * 40 + c * 8], P + rr * DD, k0 + c * 8);
                } else {
                    i32x4 zz = (i32x4){0,0,0,0};
                    *(i32x4*)&Ps[rr * 40 + c * 8] = zz;
                }
            }
            __syncthreads();
            short8 a = *(const short8*)&Xs[(wid * 16 + nn) * 40 + q * 8];
            #pragma unroll
            for (int f = 0; f < 2; f++) {
                short8 bb = *(const short8*)&Ps[(f * 16 + nn) * 40 + q * 8];
                acc[f] = __builtin_amdgcn_mfma_f32_16x16x32_bf16(a, bb, acc[f], 0, 0, 0);
            }
        }
        const int orow = mb * 64 + wid * 16 + q * 4;
        #pragma unroll
        for (int f = 0; f < 2; f++) {
            const int col = f * 16 + nn;
            #pragma unroll
            for (int r2 = 0; r2 < 4; r2++)
                O[(size_t)(orow + r2) * 32 + col] = acc[f][r2];
        }
    }
}

// ---------------------------------------------------------------------------
// pair kernel: block per (b,i); 5 waves split the 25-wide j-window.
// LN mean AND variance from precomputed moments -> rstd ready before loads
// return; single elementwise pass + single butterfly per pair.
// ---------------------------------------------------------------------------
__global__ __launch_bounds__(320) void pair_kernel(
    const float* __restrict__ E, const float* __restrict__ Cc,
    const float* __restrict__ P, const float* __restrict__ SEp,
    const float* __restrict__ SP, const float* __restrict__ SP2,
    const float* __restrict__ EC, const float* __restrict__ EP,
    const float* __restrict__ CP, const float* __restrict__ ln_g,
    const float* __restrict__ ln_b, const float* __restrict__ W_rel,
    const float* __restrict__ b_rel, float* __restrict__ out)
{
    const int wid = threadIdx.x >> 6;          // 0..4
    const int lane = threadIdx.x & 63;
    const int slot = (blockIdx.x & 7) * 512 + (blockIdx.x >> 3);  // XCD swizzle
    const int b = slot >> 7;
    const int i = slot & 127;

    const float* e_row = E + (size_t)slot * DD;

    float e[5], g[5], gb[5], wr[5];
    #pragma unroll
    for (int t = 0; t < 5; t++) {
        int d = lane + 64 * t;
        if (d < DD) {
            e[t]  = e_row[d];
            g[t]  = ln_g[d];
            gb[t] = ln_b[d];
            wr[t] = W_rel[d];
        } else {
            e[t] = 0.f; g[t] = 0.f; gb[t] = 0.f; wr[t] = 0.f;
        }
    }
    const float brel = b_rel[0];
    const float4 se4 = *(const float4*)&SEp[(size_t)slot * 8];
    const float4 sq4 = *(const float4*)&SEp[(size_t)slot * 8 + 4];
    const float SEi = se4.x + se4.y + se4.z + se4.w;
    const float SQi = sq4.x + sq4.y + sq4.z + sq4.w;
    const float* SC8 = SEp + (size_t)MM * 8;
    const float* ECb = EC + (size_t)b * LL * LL + (size_t)i * LL;

    int jlo = i - KW; if (jlo < 0) jlo = 0;
    int jhi = i + KW; if (jhi > LL - 1) jhi = LL - 1;
    const int base = b * NP + row_start(i);
    const float inv = 1.f / (float)DD;

    for (int j = jlo + wid; j <= jhi; j += 5) {
        const int bj = b * LL + j;
        const int r = j - i + KW;
        const float* c_row = Cc + (size_t)bj * DD;
        const float* p_row = P + r * DD;

        const float4 scv = *(const float4*)&SC8[(size_t)bj * 8];
        const float4 qcv = *(const float4*)&SC8[(size_t)bj * 8 + 4];
        const float ec = ECb[j];
        const float ep = EP[(size_t)slot * 32 + r];
        const float cp = CP[(size_t)bj * 32 + r];

        const float sumh = SEi + scv.x + scv.y + scv.z + scv.w + SP[r];
        const float ssq  = SQi + qcv.x + qcv.y + qcv.z + qcv.w + SP2[r]
                         + 2.f * (ec + ep + cp);

        const float mean = sumh * inv;
        float var = ssq * inv - mean * mean;
        if (var < 0.f) var = 0.f;
        const float rstd = rsqrtf(var + LN_EPS);

        float acc = 0.f;
        #pragma unroll
        for (int t = 0; t < 5; t++) {
            int d = lane + 64 * t;
            if (d < DD) {
                float h = e[t] + c_row[d] + p_row[d];
                float yv = (h - mean) * rstd * g[t] + gb[t];
                float el = yv > 0.f ? yv : (__expf(yv) - 1.f);
                acc += el * wr[t];
            }
        }
        #pragma unroll
        for (int m = 1; m < 64; m <<= 1) acc += __shfl_xor(acc, m, 64);

        if (lane == 0) out[base + (j - jlo)] = acc + brel;
    }
}

// ---------------------------------------------------------------------------
extern "C" void kernel_launch(void* const* d_in, const int* in_sizes, int n_in,
                              void* d_out, int out_size, void* d_ws, size_t ws_size,
                              hipStream_t stream) {
    const float* h_e     = (const float*)d_in[0];
    const float* h_c     = (const float*)d_in[1];
    const float* h_share = (const float*)d_in[2];
    const float* pos_emb = (const float*)d_in[3];
    const float* W_hid   = (const float*)d_in[4];
    const float* b_hid   = (const float*)d_in[5];
    const float* ln_g    = (const float*)d_in[6];
    const float* ln_b    = (const float*)d_in[7];
    const float* W_rel   = (const float*)d_in[8];
    const float* b_rel   = (const float*)d_in[9];

    float* out = (float*)d_out;

    // workspace layout (all written before read; ws is poisoned per-iter)
    float* ws  = (float*)d_ws;
    float* E   = ws;                               // MM*DD
    float* C   = E + (size_t)MM * DD;              // MM*DD
    float* P   = C + (size_t)MM * DD;              // NR*DD
    float* SEp = P + NR * DD;                      // 2*MM*8 (sum/sumsq partials)
    float* SP  = SEp + (size_t)2 * MM * 8;         // 32
    float* SP2 = SP + 32;                          // 32
    float* EC  = SP2 + 32;                         // BB*LL*LL
    float* EP  = EC + (size_t)BB * LL * LL;        // MM*32
    float* CP  = EP + (size_t)MM * 32;             // MM*32

    // 1) fused: P rows + SP/SP2 (blocks 0..24) and both MFMA GEMMs (25..280)
    fused_kernel<<<dim3(NR + 256), dim3(512), 0, stream>>>(
        h_e, h_c, h_share, pos_emb, W_hid, b_hid, E, C, P, SEp, SP, SP2);

    // 2) cross-term moment GEMMs (EC, EP, CP)
    moments_kernel<<<dim3(160), dim3(256), 0, stream>>>(E, C, P, EC, EP, CP);

    // 3) per-(b,i) block, 5 waves over the j-window: LN + ELU + dot
    pair_kernel<<<dim3(BB * LL), dim3(320), 0, stream>>>(
        E, C, P, SEp, SP, SP2, EC, EP, CP, ln_g, ln_b, W_rel, b_rel, out);
}

// Round 5
// 128.078 us; speedup vs baseline: 1.1646x; 1.1646x over previous
//
#include <hip/hip_runtime.h>
#include <math.h>

// Problem constants (fixed by setup_inputs)
#define BB 32
#define LL 128
#define DD 300
#define PD 50
#define KW 12          // window K
#define NP 3044        // number of (emo,cau) pairs for L=128, K=12
#define FF 650         // 2*D + pos_dim
#define NR 25          // 2K+1 distinct relative positions
#define KP 320         // K padded for MFMA (10 x 32)
#define MM 4096        // B*L
#define LN_EPS 1e-5f

typedef __attribute__((ext_vector_type(8))) short short8;
typedef __attribute__((ext_vector_type(4))) float f32x4;
typedef __attribute__((ext_vector_type(4))) int i32x4;

// v_cvt_pk_bf16_f32: D.lo = bf16(S0), D.hi = bf16(S1), RNE (same as old f2b)
__device__ __forceinline__ unsigned int cvtpk(float lo, float hi) {
    unsigned int r;
    asm("v_cvt_pk_bf16_f32 %0, %1, %2" : "=v"(r) : "v"(lo), "v"(hi));
    return r;
}

__device__ __forceinline__ short8 as_short8(i32x4 v) {
    union { i32x4 i; short8 s; } u; u.i = v; return u.s;
}

__device__ __forceinline__ int row_start(int i) {
    // pairs before emo-row i (L=128, K=12)
    if (i <= 12) return i * 13 + (i * (i - 1)) / 2;
    if (i <= 116) return 222 + 25 * (i - 12);
    int s = i - 116;
    return 2822 + 24 * s - (s * (s - 1)) / 2;
}

struct B8 { float f[8]; };

// ---------------------------------------------------------------------------
// fused kernel:
//   blocks 0..24     -> P[r][dd] (Gaussian-smoothed pos emb through W3) + SP[r]
//   blocks 25..280   -> MFMA GEMM  O[z][m][d] = sum_k bf16(x+share) * bf16(W)
//                       512 thr (8 waves: 4xM,2xN), dbuf LDS, 1 barrier/K-step,
//                       in-register fp32->bf16 conversion (no Wbf pass),
//                       epilogue writes per-row sums for LN-mean precompute.
// ---------------------------------------------------------------------------
__global__ __launch_bounds__(512) void fused_kernel(
    const float* __restrict__ h_e, const float* __restrict__ h_c,
    const float* __restrict__ h_share, const float* __restrict__ pos_emb,
    const float* __restrict__ W_hid, const float* __restrict__ b_hid,
    float* __restrict__ E, float* __restrict__ Cc, float* __restrict__ P,
    float* __restrict__ SEp, float* __restrict__ SP)
{
    const int tid = threadIdx.x;

    __shared__ unsigned short Bs[2][160 * 40];   // 2 x 12.8 KB, stride 40 (bank-safe)

    if (blockIdx.x < NR) {
        // ---------------- P prep (+ row sum SP) ----------------
        __shared__ float sm[PD];
        __shared__ float wsum[8];
        const int r = blockIdx.x;
        if (tid < PD) {
            float acc = 0.f;
            #pragma unroll
            for (int d2 = 0; d2 < NR; d2++) {
                int ad = d2 - KW; if (ad < 0) ad = -ad;
                float cnt = (float)(LL - ad);
                float diff = (float)(r - d2);
                acc += cnt * expf(-diff * diff) * pos_emb[d2 * PD + tid];
            }
            sm[tid] = acc;
        }
        __syncthreads();
        float mine = 0.f;
        if (tid < DD) {
            float a = b_hid[tid];
            const float* w = W_hid + (size_t)tid * FF + 2 * DD;
            #pragma unroll
            for (int k = 0; k < PD; k++) a += sm[k] * w[k];
            P[r * DD + tid] = a;
            mine = a;
        }
        #pragma unroll
        for (int m = 1; m < 64; m <<= 1) mine += __shfl_xor(mine, m, 64);
        if ((tid & 63) == 0) wsum[tid >> 6] = mine;
        __syncthreads();
        if (tid == 0) {
            float s = 0.f;
            #pragma unroll
            for (int w = 0; w < 8; w++) s += wsum[w];
            SP[r] = s;
        }
        return;
    }

    // ---------------- GEMM ----------------
    const int gb = blockIdx.x - NR;                 // 0..255
    const int sg = (gb & 7) * 32 + (gb >> 3);      // XCD-chunked swizzle (256%8==0)
    const int m0 = (sg & 63) * 64;
    const int y  = (sg >> 6) & 1;
    const int z  = sg >> 7;
    const int n0 = y * 160;

    const int wid  = tid >> 6;
    const int lane = tid & 63;
    const int wm = wid & 3;          // M sub-tile (4 x 16)
    const int wn = wid >> 1 >> 1;    // N half (2 x 80)
    const int nn = lane & 15;
    const int q  = lane >> 4;

    const int row = m0 + wm * 16 + nn;
    const float* xr = (z ? h_c : h_e) + (size_t)row * DD;
    const float* sr = h_share + (size_t)row * DD;
    const float* Wsrc = W_hid + z * DD;

    // staging geometry: 640 items (n=0..159, c=0..3); item a = tid, item b = tid+512
    const int n_a = tid >> 2,        c_a = tid & 3;
    const int d_a = n0 + n_a;                      // always < 300 (max 287)
    const int n_b = (tid + 512) >> 2;
    const int d_b = n0 + n_b;                      // needs <300 guard when n0=160
    const bool has_b = (tid < 128);

    B8 ra, rb;
    float4 ax0, ax1, as0, as1;

    auto loadB = [&](int k0) {
        const float* pa = Wsrc + (size_t)d_a * FF + k0 + c_a * 8;  // 8B aligned
        float2 u0 = *(const float2*)(pa);
        float2 u1 = *(const float2*)(pa + 2);
        float2 u2 = *(const float2*)(pa + 4);
        float2 u3 = *(const float2*)(pa + 6);
        ra.f[0] = u0.x; ra.f[1] = u0.y; ra.f[2] = u1.x; ra.f[3] = u1.y;
        ra.f[4] = u2.x; ra.f[5] = u2.y; ra.f[6] = u3.x; ra.f[7] = u3.y;
        if (has_b) {
            if (d_b < DD) {
                const float* pb = Wsrc + (size_t)d_b * FF + k0 + c_a * 8;
                float2 v0 = *(const float2*)(pb);
                float2 v1 = *(const float2*)(pb + 2);
                float2 v2 = *(const float2*)(pb + 4);
                float2 v3 = *(const float2*)(pb + 6);
                rb.f[0] = v0.x; rb.f[1] = v0.y; rb.f[2] = v1.x; rb.f[3] = v1.y;
                rb.f[4] = v2.x; rb.f[5] = v2.y; rb.f[6] = v3.x; rb.f[7] = v3.y;
            } else {
                #pragma unroll
                for (int u = 0; u < 8; u++) rb.f[u] = 0.f;
            }
        }
    };

    auto writeB = [&](int buf) {
        i32x4 w;
        w[0] = cvtpk(ra.f[0], ra.f[1]); w[1] = cvtpk(ra.f[2], ra.f[3]);
        w[2] = cvtpk(ra.f[4], ra.f[5]); w[3] = cvtpk(ra.f[6], ra.f[7]);
        *(i32x4*)&Bs[buf][n_a * 40 + c_a * 8] = w;
        if (has_b) {
            i32x4 v;
            v[0] = cvtpk(rb.f[0], rb.f[1]); v[1] = cvtpk(rb.f[2], rb.f[3]);
            v[2] = cvtpk(rb.f[4], rb.f[5]); v[3] = cvtpk(rb.f[6], rb.f[7]);
            *(i32x4*)&Bs[buf][n_b * 40 + c_a * 8] = v;
        }
    };

    auto loadA = [&](int k0) {
        const int kb = k0 + q * 8;
        if (kb + 7 < DD) {
            ax0 = *(const float4*)&xr[kb];
            ax1 = *(const float4*)&xr[kb + 4];
            as0 = *(const float4*)&sr[kb];
            as1 = *(const float4*)&sr[kb + 4];
        } else {
            float t[8], u[8];
            #pragma unroll
            for (int uu = 0; uu < 8; uu++) {
                int k = kb + uu;
                t[uu] = (k < DD) ? xr[k] : 0.f;
                u[uu] = (k < DD) ? sr[k] : 0.f;
            }
            ax0 = make_float4(t[0], t[1], t[2], t[3]);
            ax1 = make_float4(t[4], t[5], t[6], t[7]);
            as0 = make_float4(u[0], u[1], u[2], u[3]);
            as1 = make_float4(u[4], u[5], u[6], u[7]);
        }
    };

    f32x4 acc[5];
    #pragma unroll
    for (int f = 0; f < 5; f++) acc[f] = (f32x4){0.f, 0.f, 0.f, 0.f};

    // prologue: stage chunk 0
    loadB(0);
    loadA(0);
    writeB(0);
    __syncthreads();

    #pragma unroll
    for (int k0i = 0; k0i < 10; k0i++) {
        const int cb = k0i & 1;
        const bool more = (k0i < 9);
        const int kn = (k0i + 1) * 32;

        if (more) loadB(kn);                 // next B chunk -> regs (in flight)

        i32x4 af;                            // A frag from prefetched regs
        af[0] = cvtpk(ax0.x + as0.x, ax0.y + as0.y);
        af[1] = cvtpk(ax0.z + as0.z, ax0.w + as0.w);
        af[2] = cvtpk(ax1.x + as1.x, ax1.y + as1.y);
        af[3] = cvtpk(ax1.z + as1.z, ax1.w + as1.w);
        short8 a = as_short8(af);

        if (more) loadA(kn);                 // next A chunk -> regs (in flight)

        #pragma unroll
        for (int f = 0; f < 5; f++) {
            short8 b = *(const short8*)&Bs[cb][(wn * 80 + f * 16 + nn) * 40 + q * 8];
            acc[f] = __builtin_amdgcn_mfma_f32_16x16x32_bf16(a, b, acc[f], 0, 0, 0);
        }

        if (more) {
            writeB(cb ^ 1);                  // convert + ds_write next buffer
            __syncthreads();                 // one barrier per K-step
        }
    }

    // epilogue 1: per-row sums (for LN-mean precompute), 4-step butterfly over nn
    const int orow = m0 + wm * 16 + q * 4;   // C/D: row = (lane>>4)*4 + reg
    float rs[4];
    #pragma unroll
    for (int r2 = 0; r2 < 4; r2++) {
        float v = 0.f;
        #pragma unroll
        for (int f = 0; f < 5; f++) v += acc[f][r2];
        #pragma unroll
        for (int m = 1; m < 16; m <<= 1) v += __shfl_xor(v, m, 64);
        rs[r2] = v;
    }
    if (nn == 0) {
        float* slot = SEp + (size_t)(((z * 2 + y) * 2 + wn)) * MM;
        #pragma unroll
        for (int r2 = 0; r2 < 4; r2++) slot[orow + r2] = rs[r2];
    }

    // epilogue 2: C write
    float* O = z ? Cc : E;
    #pragma unroll
    for (int f = 0; f < 5; f++) {
        int col = n0 + wn * 80 + f * 16 + nn;  // C/D: col = lane&15
        if (col < DD) {
            #pragma unroll
            for (int r2 = 0; r2 < 4; r2++)
                O[(size_t)(orow + r2) * DD + col] = acc[f][r2];
        }
    }
}

// ---------------------------------------------------------------------------
// pair kernel: block per (b, i); 5 waves split the 25-wide j-window evenly.
// LN mean from precomputed row sums (SEp/SP) -> only 2 butterflies per pair.
// ---------------------------------------------------------------------------
__global__ __launch_bounds__(320) void pair_kernel(
    const float* __restrict__ E, const float* __restrict__ Cc,
    const float* __restrict__ P, const float* __restrict__ SEp,
    const float* __restrict__ SP, const float* __restrict__ ln_g,
    const float* __restrict__ ln_b, const float* __restrict__ W_rel,
    const float* __restrict__ b_rel, float* __restrict__ out)
{
    const int wid = threadIdx.x >> 6;          // 0..4
    const int lane = threadIdx.x & 63;
    const int slot = (blockIdx.x & 7) * 512 + (blockIdx.x >> 3);  // XCD swizzle
    const int b = slot >> 7;
    const int i = slot & 127;

    const float* e_row = E + (size_t)slot * DD;

    float e[5], g[5], gb[5], wr[5];
    #pragma unroll
    for (int t = 0; t < 5; t++) {
        int d = lane + 64 * t;
        if (d < DD) {
            e[t]  = e_row[d];
            g[t]  = ln_g[d];
            gb[t] = ln_b[d];
            wr[t] = W_rel[d];
        } else {
            e[t] = 0.f; g[t] = 0.f; gb[t] = 0.f; wr[t] = 0.f;
        }
    }
    const float brel = b_rel[0];
    const float SEi = SEp[slot] + SEp[MM + slot] + SEp[2 * MM + slot] + SEp[3 * MM + slot];
    const float* SC = SEp + 4 * MM;

    int jlo = i - KW; if (jlo < 0) jlo = 0;
    int jhi = i + KW; if (jhi > LL - 1) jhi = LL - 1;
    const int base = b * NP + row_start(i);
    const float inv = 1.f / (float)DD;

    for (int j = jlo + wid; j <= jhi; j += 5) {
        const int bj = b * LL + j;
        const int r = j - i + KW;
        const float* c_row = Cc + (size_t)bj * DD;
        const float* p_row = P + r * DD;

        const float sumh = SEi + SC[bj] + SC[MM + bj] + SC[2 * MM + bj]
                         + SC[3 * MM + bj] + SP[r];

        float h[5];
        float ss = 0.f;
        #pragma unroll
        for (int t = 0; t < 5; t++) {
            int d = lane + 64 * t;
            h[t] = 0.f;
            if (d < DD) {
                h[t] = e[t] + c_row[d] + p_row[d];
                ss += h[t] * h[t];
            }
        }
        #pragma unroll
        for (int m = 1; m < 64; m <<= 1) ss += __shfl_xor(ss, m, 64);

        const float mean = sumh * inv;
        float var = ss * inv - mean * mean;
        if (var < 0.f) var = 0.f;
        const float rstd = rsqrtf(var + LN_EPS);

        float acc = 0.f;
        #pragma unroll
        for (int t = 0; t < 5; t++) {
            int d = lane + 64 * t;
            if (d < DD) {
                float yv = (h[t] - mean) * rstd * g[t] + gb[t];
                float el = yv > 0.f ? yv : (__expf(yv) - 1.f);
                acc += el * wr[t];
            }
        }
        #pragma unroll
        for (int m = 1; m < 64; m <<= 1) acc += __shfl_xor(acc, m, 64);

        if (lane == 0) out[base + (j - jlo)] = acc + brel;
    }
}

// ---------------------------------------------------------------------------
extern "C" void kernel_launch(void* const* d_in, const int* in_sizes, int n_in,
                              void* d_out, int out_size, void* d_ws, size_t ws_size,
                              hipStream_t stream) {
    const float* h_e     = (const float*)d_in[0];
    const float* h_c     = (const float*)d_in[1];
    const float* h_share = (const float*)d_in[2];
    const float* pos_emb = (const float*)d_in[3];
    const float* W_hid   = (const float*)d_in[4];
    const float* b_hid   = (const float*)d_in[5];
    const float* ln_g    = (const float*)d_in[6];
    const float* ln_b    = (const float*)d_in[7];
    const float* W_rel   = (const float*)d_in[8];
    const float* b_rel   = (const float*)d_in[9];

    float* out = (float*)d_out;

    // workspace layout (all written before read; ws is poisoned per-iter)
    float* ws  = (float*)d_ws;
    float* E   = ws;                              // 4096*300 f32
    float* C   = E + (size_t)MM * DD;             // 4096*300 f32
    float* P   = C + (size_t)MM * DD;             // 25*300 f32
    float* SEp = P + NR * DD;                     // 8*4096 f32 row sums (z,y,wn)
    float* SP  = SEp + 8 * MM;                    // 25 f32

    // 1) fused: P rows + SP (blocks 0..24) and both MFMA GEMMs (blocks 25..280)
    fused_kernel<<<dim3(NR + 256), dim3(512), 0, stream>>>(
        h_e, h_c, h_share, pos_emb, W_hid, b_hid, E, C, P, SEp, SP);

    // 2) per-(b,i) block, 5 waves over the j-window: LN + ELU + dot
    pair_kernel<<<dim3(BB * LL), dim3(320), 0, stream>>>(
        E, C, P, SEp, SP, ln_g, ln_b, W_rel, b_rel, out);
}